// Round 1
// 13585.574 us; speedup vs baseline: 1.2676x; 1.2676x over previous
//
#include <hip/hip_runtime.h>
#include <math.h>

#define BB 4
#define DD 8
#define HH 192
#define WW 192
#define HWSZ (HH*WW)

__device__ __forceinline__ float sigm(float x){ return 1.f/(1.f+__expf(-x)); }
__device__ __forceinline__ float tanh_fast(float x){ return 1.f - 2.f/(1.f+__expf(2.f*x)); }

// ---------------------------------------------------------------------------
// prep: transpose weights into [cin][tap][cout] layouts (contiguous in cout)
// GW: gates combined [40][9][56]  (o order: f0-7, i0-7, g0-7, q0-31)
// T0/T1: [40][25][40]   TH: [40][9][8]   T2: [40][25][3]
// ---------------------------------------------------------------------------
__global__ void prep_kernel(const float* __restrict__ Wf, const float* __restrict__ Wi,
                            const float* __restrict__ Wc, const float* __restrict__ Wq,
                            const float* __restrict__ W0, const float* __restrict__ W1,
                            const float* __restrict__ Wh, const float* __restrict__ W2,
                            float* __restrict__ GW, float* __restrict__ T0,
                            float* __restrict__ T1, float* __restrict__ TH,
                            float* __restrict__ T2)
{
    int i = blockIdx.x * 256 + threadIdx.x;
    const int nGW = 40*9*56;
    const int nT  = 40*25*40;
    const int nTH = 40*9*8;
    const int nT2 = 40*25*3;
    if (i < nGW) {
        int c = i / (9*56); int rem = i % (9*56); int t = rem / 56; int o = rem % 56;
        float v;
        if      (o < 8)  v = Wf[((o     )*40 + c)*9 + t];
        else if (o < 16) v = Wi[((o -  8)*40 + c)*9 + t];
        else if (o < 24) v = Wc[((o - 16)*40 + c)*9 + t];
        else             v = Wq[((o - 24)*40 + c)*9 + t];
        GW[i] = v;
        return;
    }
    i -= nGW;
    if (i < nT) {
        int c = i / 1000; int rem = i % 1000; int t = rem / 40; int o = rem % 40;
        T0[i] = W0[((o*40 + c)*25) + t];
        return;
    }
    i -= nT;
    if (i < nT) {
        int c = i / 1000; int rem = i % 1000; int t = rem / 40; int o = rem % 40;
        T1[i] = W1[((o*40 + c)*25) + t];
        return;
    }
    i -= nT;
    if (i < nTH) {
        int c = i / 72; int rem = i % 72; int t = rem / 8; int o = rem % 8;
        TH[i] = Wh[((o*40 + c)*9) + t];
        return;
    }
    i -= nTH;
    if (i < nT2) {
        int c = i / 75; int rem = i % 75; int t = rem / 3; int o = rem % 3;
        T2[i] = W2[((o*40 + c)*25) + t];
        return;
    }
}

// ---------------------------------------------------------------------------
// gates: 1-wave blocks, tile 8x8, cin chunks of 8 staged in LDS (3.2KB)
// ---------------------------------------------------------------------------
__global__ __launch_bounds__(64, 4) void gates_kernel(
    const float* __restrict__ xin, const float* __restrict__ hsin,
    float* __restrict__ cs, float* __restrict__ r,
    const float* __restrict__ GW,
    const float* __restrict__ bf, const float* __restrict__ bi_,
    const float* __restrict__ bc, const float* __restrict__ bq,
    int tstep)
{
    __shared__ float tile[8*10*10];
    int blk = blockIdx.x;
    int bi = blk / 576; int tl = blk % 576;
    int h0 = (tl / 24) * 8, w0 = (tl % 24) * 8;
    int lane = threadIdx.x;
    int ty = lane >> 3, tx = lane & 7;

    float acc[56];
#pragma unroll
    for (int o = 0; o < 56; ++o) acc[o] = 0.f;

#pragma unroll 1
    for (int ch = 0; ch < 5; ++ch) {
        __syncthreads();
#pragma unroll 1
        for (int i = lane; i < 800; i += 64) {
            int c = i / 100; int rem = i % 100; int ry = rem / 10; int rx = rem % 10;
            int gh = h0 + ry - 1, gw = w0 + rx - 1;
            int cg = ch*8 + c;
            float v = 0.f;
            if ((unsigned)gh < (unsigned)HH && (unsigned)gw < (unsigned)WW) {
                if (cg < 32) v = xin[(((size_t)(bi*DD + tstep))*32 + cg)*HWSZ + gh*WW + gw];
                else         v = hsin[((size_t)(bi*8 + (cg-32)))*HWSZ + gh*WW + gw];
            }
            tile[i] = v;
        }
        __syncthreads();
#pragma unroll 1
        for (int c = 0; c < 8; ++c) {
            const float* wc = GW + (ch*8 + c)*(9*56);
            const float* bp = tile + c*100 + ty*10 + tx;
#pragma unroll
            for (int t = 0; t < 9; ++t) {
                float x = bp[(t/3)*10 + (t%3)];
                const float* wp = wc + t*56;
#pragma unroll
                for (int o = 0; o < 56; ++o) acc[o] = fmaf(x, wp[o], acc[o]);
            }
        }
    }

    int h = h0 + ty, w = w0 + tx;
    size_t pix = (size_t)h*WW + w;
#pragma unroll
    for (int o = 0; o < 8; ++o) {
        float f  = sigm(acc[o]      + bf[o]);
        float ii = sigm(acc[8 + o]  + bi_[o]);
        float gg = tanh_fast(acc[16 + o] + bc[o]);
        size_t ci = ((size_t)(bi*8 + o))*HWSZ + pix;
        float cn = f * cs[ci] + ii * gg;
        cs[ci] = cn;
        r[((size_t)(bi*40 + o))*HWSZ + pix] = cn;
    }
#pragma unroll
    for (int o = 0; o < 32; ++o) {
        r[((size_t)(bi*40 + 8 + o))*HWSZ + pix] = sigm(acc[24 + o] + bq[o]);
    }
}

// ---------------------------------------------------------------------------
// conv5 v2: 512-thread blocks (8 waves), 16x16 output tile, 1 px/thread,
// couts split 2 ways across waves (20 per thread). Weights for each cin-chunk
// staged in LDS (32KB) -> inner weight reads are wave-uniform ds_read_b128
// broadcasts. 576 blocks * 8 waves = 4608 waves = 4.5 waves/SIMD (vs 1.1).
// AFFINE: BN scale/shift from binned stats folded into the staging load.
// ---------------------------------------------------------------------------
template<bool AFFINE>
__global__ __launch_bounds__(512, 4) void conv5_kernel(
    const float* __restrict__ in, const float* __restrict__ Tw,
    const float* __restrict__ statsIn, const float* __restrict__ g,
    const float* __restrict__ be,
    float* __restrict__ out, float* __restrict__ statsOut)
{
    __shared__ float wlds[8000];          // 8 cin * 25 taps * 40 cout
    __shared__ float tlds[3200];          // 8 cin * 20 * 20
    __shared__ float sc[40], sh[40];
    __shared__ float bstat[80];

    int blk = blockIdx.x;
    int bi = blk / 144; int tl = blk % 144;         // 12 x 12 tiles of 16x16
    int h0 = (tl / 12) * 16, w0 = (tl % 12) * 16;
    int tid = threadIdx.x;
    int lane = tid & 63, wave = tid >> 6;
    int cg = wave >> 2;                              // cout group 0/1
    int pyr = ((wave & 3) << 2) | (lane >> 4);       // 0..15 tile row
    int pxc = lane & 15;                             // 0..15 tile col

    if (AFFINE) {
        if (tid < 40) {
            float s = 0.f, s2 = 0.f;
#pragma unroll
            for (int bn = 0; bn < 8; ++bn) {
                s  += statsIn[bn*80 + tid];
                s2 += statsIn[bn*80 + 40 + tid];
            }
            const float N = (float)(BB * HWSZ);
            float m = s / N;
            float v = fmaxf(s2 / N - m*m, 0.f);
            float scv = g[tid] * rsqrtf(v + 1e-5f);
            sc[tid] = scv;
            sh[tid] = be[tid] - m * scv;
        }
    }
    if (tid < 80) bstat[tid] = 0.f;

    float acc[20];
#pragma unroll
    for (int o = 0; o < 20; ++o) acc[o] = 0.f;

#pragma unroll 1
    for (int ch = 0; ch < 5; ++ch) {
        __syncthreads();
        // stage weight chunk: contiguous, coalesced
#pragma unroll 1
        for (int i = tid; i < 8000; i += 512) wlds[i] = Tw[ch*8000 + i];
        // stage input tile (with BN+ReLU fold when AFFINE)
#pragma unroll 1
        for (int i = tid; i < 3200; i += 512) {
            int c = i / 400; int rem = i % 400; int ry = rem / 20; int rx = rem % 20;
            int gh = h0 + ry - 2, gw = w0 + rx - 2;
            float v = 0.f;
            if ((unsigned)gh < (unsigned)HH && (unsigned)gw < (unsigned)WW) {
                int cc = ch*8 + c;
                v = in[((size_t)(bi*40 + cc))*HWSZ + gh*WW + gw];
                if (AFFINE) v = fmaxf(0.f, fmaf(v, sc[cc], sh[cc]));
            }
            tlds[i] = v;
        }
        __syncthreads();
#pragma unroll 1
        for (int c = 0; c < 8; ++c) {
            const float* wb = wlds + c*1000 + cg*20;
            const float* bp = tlds + c*400 + pyr*20 + pxc;
#pragma unroll
            for (int t = 0; t < 25; ++t) {
                float x = bp[(t/5)*20 + (t%5)];
                const float* wp = wb + t*40;
#pragma unroll
                for (int o = 0; o < 20; ++o) acc[o] = fmaf(x, wp[o], acc[o]);
            }
        }
    }

    int h = h0 + pyr, w = w0 + pxc;
    size_t pix = (size_t)h*WW + w;
#pragma unroll
    for (int o = 0; o < 20; ++o)
        out[((size_t)(bi*40 + cg*20 + o))*HWSZ + pix] = acc[o];

    // binned BN-stats: wave shuffle reduce -> LDS -> one atomic per slot
#pragma unroll
    for (int o = 0; o < 20; ++o) {
        float s  = acc[o];
        float s2 = acc[o]*acc[o];
#pragma unroll
        for (int off = 32; off > 0; off >>= 1) {
            s  += __shfl_down(s,  off);
            s2 += __shfl_down(s2, off);
        }
        if (lane == 0) {
            atomicAdd(&bstat[cg*20 + o], s);
            atomicAdd(&bstat[40 + cg*20 + o], s2);
        }
    }
    __syncthreads();
    if (tid < 80) atomicAdd(&statsOut[(blk & 7)*80 + tid], bstat[tid]);
}

// ---------------------------------------------------------------------------
// head: 1-wave blocks, tile 8x16, 2 px/thread; BN1(from stats)+ReLU folded
// into load; computes hs (3x3, 8ch) and p_depth output (5x5, 3ch).
// ---------------------------------------------------------------------------
__global__ __launch_bounds__(64, 4) void head_kernel(
    const float* __restrict__ y1, const float* __restrict__ statsIn,
    const float* __restrict__ g, const float* __restrict__ be,
    const float* __restrict__ TH, const float* __restrict__ T2,
    const float* __restrict__ bh, const float* __restrict__ b2,
    float* __restrict__ hsout, float* __restrict__ outp, int tstep)
{
    __shared__ float tile[8*12*20];
    __shared__ float sc[40], sh[40];
    int blk = blockIdx.x;
    int bi = blk / 288; int tl = blk % 288;
    int h0 = (tl / 12) * 8, w0 = (tl % 12) * 16;
    int lane = threadIdx.x;
    int ty = lane >> 4, tx = lane & 15;

    if (lane < 40) {
        float s = 0.f, s2 = 0.f;
#pragma unroll
        for (int bn = 0; bn < 8; ++bn) {
            s  += statsIn[bn*80 + lane];
            s2 += statsIn[bn*80 + 40 + lane];
        }
        const float N = (float)(BB * HWSZ);
        float m = s / N;
        float v = fmaxf(s2 / N - m*m, 0.f);
        float scv = g[lane] * rsqrtf(v + 1e-5f);
        sc[lane] = scv;
        sh[lane] = be[lane] - m * scv;
    }
    __syncthreads();

    float aH0[8], aH1[8], aO0[3], aO1[3];
#pragma unroll
    for (int o = 0; o < 8; ++o) { aH0[o] = 0.f; aH1[o] = 0.f; }
#pragma unroll
    for (int o = 0; o < 3; ++o) { aO0[o] = 0.f; aO1[o] = 0.f; }

#pragma unroll 1
    for (int ch = 0; ch < 5; ++ch) {
        __syncthreads();
#pragma unroll 1
        for (int i = lane; i < 1920; i += 64) {
            int c = i / 240; int rem = i % 240; int ry = rem / 20; int rx = rem % 20;
            int gh = h0 + ry - 2, gw = w0 + rx - 2;
            float v = 0.f;
            if ((unsigned)gh < (unsigned)HH && (unsigned)gw < (unsigned)WW) {
                v = y1[((size_t)(bi*40 + ch*8 + c))*HWSZ + gh*WW + gw];
                v = fmaxf(0.f, fmaf(v, sc[ch*8 + c], sh[ch*8 + c]));
            }
            tile[i] = v;
        }
        __syncthreads();
#pragma unroll 1
        for (int c = 0; c < 8; ++c) {
            const float* w2c = T2 + (ch*8 + c)*75;
            const float* whc = TH + (ch*8 + c)*72;
            const float* bp = tile + c*240 + ty*20 + tx;
#pragma unroll
            for (int t = 0; t < 25; ++t) {
                int dy = t/5, dx = t%5;
                float x0 = bp[dy*20 + dx];
                float x1 = bp[dy*20 + dx + 80];
                const float* wp2 = w2c + t*3;
#pragma unroll
                for (int o = 0; o < 3; ++o) {
                    aO0[o] = fmaf(x0, wp2[o], aO0[o]);
                    aO1[o] = fmaf(x1, wp2[o], aO1[o]);
                }
                if (dy >= 1 && dy <= 3 && dx >= 1 && dx <= 3) {
                    const float* wph = whc + ((dy-1)*3 + (dx-1))*8;
#pragma unroll
                    for (int o = 0; o < 8; ++o) {
                        aH0[o] = fmaf(x0, wph[o], aH0[o]);
                        aH1[o] = fmaf(x1, wph[o], aH1[o]);
                    }
                }
            }
        }
    }

    int h = h0 + ty, w = w0 + tx;
#pragma unroll
    for (int o = 0; o < 8; ++o) {
        size_t base = ((size_t)(bi*8 + o))*HWSZ + (size_t)h*WW + w;
        hsout[base] = aH0[o] + bh[o];
        hsout[base + 4*WW] = aH1[o] + bh[o];
    }
#pragma unroll
    for (int o = 0; o < 3; ++o) {
        size_t base = (((size_t)(bi*3 + o))*DD + tstep)*HWSZ + (size_t)h*WW + w;
        outp[base] = aO0[o] + b2[o];
        outp[base + 4*WW] = aO1[o] + b2[o];
    }
}

// ---------------------------------------------------------------------------
extern "C" void kernel_launch(void* const* d_in, const int* in_sizes, int n_in,
                              void* d_out, int out_size, void* d_ws, size_t ws_size,
                              hipStream_t stream)
{
    const float* in1 = (const float*)d_in[0];
    const float* in2 = (const float*)d_in[1];
    const float* Wf  = (const float*)d_in[2];
    const float* bf  = (const float*)d_in[3];
    const float* Wi  = (const float*)d_in[4];
    const float* bi  = (const float*)d_in[5];
    const float* Wc  = (const float*)d_in[6];
    const float* bc  = (const float*)d_in[7];
    const float* Wq  = (const float*)d_in[8];
    const float* bq  = (const float*)d_in[9];
    const float* W0  = (const float*)d_in[10];
    const float* g0  = (const float*)d_in[11];
    const float* be0 = (const float*)d_in[12];
    const float* W1  = (const float*)d_in[13];
    const float* g1  = (const float*)d_in[14];
    const float* be1 = (const float*)d_in[15];
    const float* W2  = (const float*)d_in[16];
    const float* b2w = (const float*)d_in[17];
    const float* Wh  = (const float*)d_in[18];
    const float* bh  = (const float*)d_in[19];

    float* ws    = (float*)d_ws;
    float* stats = ws;                              // 32 steps * 1280 = 40960
    float* hs    = ws + 40960;
    float* cs    = hs + (size_t)BB*8*HWSZ;
    float* r     = cs + (size_t)BB*8*HWSZ;
    float* y0    = r  + (size_t)BB*40*HWSZ;
    float* y1    = y0 + (size_t)BB*40*HWSZ;
    float* GW    = y1 + (size_t)BB*40*HWSZ;
    float* T0    = GW + 40*9*56;
    float* T1    = T0 + 40*25*40;
    float* TH    = T1 + 40*25*40;
    float* T2    = TH + 40*9*8;

    // zero: stats + hs + cs (contiguous prefix of ws)
    hipMemsetAsync(d_ws, 0, (40960 + (size_t)2*BB*8*HWSZ) * sizeof(float), stream);

    prep_kernel<<<(106040 + 255)/256, 256, 0, stream>>>(Wf, Wi, Wc, Wq, W0, W1, Wh, W2,
                                                        GW, T0, T1, TH, T2);

    float* out = (float*)d_out;
    const size_t o2off = (size_t)BB*3*DD*HWSZ;

    for (int t = 0; t < DD; ++t) {
        for (int s = 0; s < 2; ++s) {
            const float* xin = s ? in2 : in1;
            float* ob = out + (s ? o2off : 0);
            float* st = stats + (size_t)(t*2 + s)*1280;

            gates_kernel<<<2304, 64, 0, stream>>>(xin, hs, cs, r, GW, bf, bi, bc, bq, t);
            conv5_kernel<false><<<576, 512, 0, stream>>>(r, T0, nullptr, nullptr, nullptr,
                                                         y0, st);
            conv5_kernel<true><<<576, 512, 0, stream>>>(y0, T1, st, g0, be0,
                                                        y1, st + 640);
            head_kernel<<<1152, 64, 0, stream>>>(y1, st + 640, g1, be1, TH, T2,
                                                 bh, b2w, hs, ob, t);
        }
    }
}